// Round 11
// baseline (660.820 us; speedup 1.0000x reference)
//
#include <hip/hip_runtime.h>
#include <hip/hip_bf16.h>
#include <math.h>

// CrossTransformer block. Round 11: GEMM K-loop -> triple-buffered LDS with
// counted s_waitcnt vmcnt(N) + raw s_barrier (T3/T4): tile t+1's loads stay
// in flight across the barrier instead of the __syncthreads full drain.
// B=4, SQ=1024, SK=2048, C=1024, H=16, DH=64.

namespace {
constexpr int BB  = 4;
constexpr int SQ_ = 1024;
constexpr int SK_ = 2048;
constexpr int CC  = 1024;
constexpr int HH  = 16;
constexpr float SCALE  = 0.03125f;   // 1/sqrt(1024)
constexpr float LN_EPS = 1e-5f;
}

typedef __hip_bfloat16 bf16;
typedef __attribute__((ext_vector_type(8))) short short8;
typedef __attribute__((ext_vector_type(4))) float f32x4;

__device__ __forceinline__ void gload16(const void* g, void* l) {
    __builtin_amdgcn_global_load_lds((const __attribute__((address_space(1))) unsigned int*)g,
                                     (__attribute__((address_space(3))) unsigned int*)l,
                                     16, 0, 0);
}

// ---------------- all fp32 -> bf16 conversions in one kernel ----------------
#define MAXJOBS 10
struct CvtJobs {
    const float* src[MAXJOBS];
    bf16*        dst[MAXJOBS];
    int          end[MAXJOBS];   // cumulative n8 (elements/8)
    int          njobs;
};

__global__ __launch_bounds__(256)
void cvt_all(CvtJobs J) {
    const int i = blockIdx.x * 256 + threadIdx.x;
    if (i >= J.end[J.njobs - 1]) return;
    int j = 0;
    while (i >= J.end[j]) ++j;
    const int base = j ? J.end[j - 1] : 0;
    const int k = i - base;
    const float4 a = ((const float4*)J.src[j])[2 * k];
    const float4 b = ((const float4*)J.src[j])[2 * k + 1];
    union { ushort4 v; bf16 h[4]; } lo, hi;
    lo.h[0] = __float2bfloat16(a.x); lo.h[1] = __float2bfloat16(a.y);
    lo.h[2] = __float2bfloat16(a.z); lo.h[3] = __float2bfloat16(a.w);
    hi.h[0] = __float2bfloat16(b.x); hi.h[1] = __float2bfloat16(b.y);
    hi.h[2] = __float2bfloat16(b.z); hi.h[3] = __float2bfloat16(b.w);
    ((ushort4*)J.dst[j])[2 * k]     = lo.v;
    ((ushort4*)J.dst[j])[2 * k + 1] = hi.v;
}

// ---------------- LayerNorm (+optional SiLU), bf16 out, vector loads --------
__device__ __forceinline__ float4 ld4(const float* p, int idx) {
    return ((const float4*)p)[idx];
}
__device__ __forceinline__ float4 ld4(const bf16* p, int idx) {
    const ushort4 u = ((const ushort4*)p)[idx];
    float4 r;
    r.x = __bfloat162float(*(const bf16*)&u.x);
    r.y = __bfloat162float(*(const bf16*)&u.y);
    r.z = __bfloat162float(*(const bf16*)&u.z);
    r.w = __bfloat162float(*(const bf16*)&u.w);
    return r;
}

template<int NCOLS, typename TI>
__global__ __launch_bounds__(256)
void ln_kernel(const TI* __restrict__ x, const float* __restrict__ g,
               const float* __restrict__ b, bf16* __restrict__ out, int do_silu) {
    constexpr int PER = NCOLS / 1024;   // 4-elem chunks per thread
    const size_t row = blockIdx.x;
    const TI* xr = x + row * NCOLS;
    float4 vals[PER];
    float s = 0.f, ss = 0.f;
#pragma unroll
    for (int i = 0; i < PER; ++i) {
        vals[i] = ld4(xr, threadIdx.x + i * 256);
        s  += vals[i].x + vals[i].y + vals[i].z + vals[i].w;
        ss += vals[i].x * vals[i].x + vals[i].y * vals[i].y
            + vals[i].z * vals[i].z + vals[i].w * vals[i].w;
    }
    for (int off = 32; off > 0; off >>= 1) {
        s  += __shfl_down(s, off, 64);
        ss += __shfl_down(ss, off, 64);
    }
    __shared__ float red[10];
    const int wid = threadIdx.x >> 6, lane = threadIdx.x & 63;
    if (lane == 0) { red[wid] = s; red[wid + 4] = ss; }
    __syncthreads();
    if (threadIdx.x == 0) {
        const float ts  = red[0] + red[1] + red[2] + red[3];
        const float tss = red[4] + red[5] + red[6] + red[7];
        const float mu  = ts / NCOLS;
        const float var = tss / NCOLS - mu * mu;
        red[8] = mu;
        red[9] = rsqrtf(var + LN_EPS);
    }
    __syncthreads();
    const float mu = red[8], rstd = red[9];
    bf16* outr = out + row * NCOLS;
#pragma unroll
    for (int i = 0; i < PER; ++i) {
        const int c = (threadIdx.x + i * 256) * 4;
        const float4 gg = *(const float4*)(g + c);
        const float4 bb = *(const float4*)(b + c);
        float y0 = (vals[i].x - mu) * rstd * gg.x + bb.x;
        float y1 = (vals[i].y - mu) * rstd * gg.y + bb.y;
        float y2 = (vals[i].z - mu) * rstd * gg.z + bb.z;
        float y3 = (vals[i].w - mu) * rstd * gg.w + bb.w;
        if (do_silu) {
            y0 = y0 / (1.f + __expf(-y0));
            y1 = y1 / (1.f + __expf(-y1));
            y2 = y2 / (1.f + __expf(-y2));
            y3 = y3 / (1.f + __expf(-y3));
        }
        union { ushort4 v; bf16 h[4]; } pk;
        pk.h[0] = __float2bfloat16(y0); pk.h[1] = __float2bfloat16(y1);
        pk.h[2] = __float2bfloat16(y2); pk.h[3] = __float2bfloat16(y3);
        *(ushort4*)(outr + c) = pk.v;
    }
}

// ------------- bf16 MFMA GEMM: C[M,N] = A[M,K] @ B[N,K]^T (+bias)(+resid) ---
// Triple-buffered K-loop with counted vmcnt: iteration t waits only for its
// own tile's loads (vmcnt(NLD) leaves tile t+1 in flight), raw s_barrier,
// stages tile t+2, then MFMAs tile t. Buffer (t+2)%3 was last read in iter
// t-1, which all waves completed before this barrier -> no race.
// BMT = 128 (2x2 waves) or 64 (1x4 waves). XCD-swizzled blockIdx (%8==0).
// VMODE (OUT16 only): v-columns written TRANSPOSED into Vt instead of C.
template<int OUT16, int BMT, int VMODE>
__global__ __launch_bounds__(256)
void gemm_bt16(const bf16* __restrict__ A, const bf16* __restrict__ B,
               void* __restrict__ Cv, int M, int N, int K,
               const float* __restrict__ bias, const float* __restrict__ resid,
               bf16* __restrict__ Vt, int ldt) {
    constexpr int WC = (BMT == 128) ? 2 : 4;   // waves in N dir
    constexpr int NF = (BMT == 128) ? 4 : 2;   // 16-col fragments per wave
    __shared__ bf16 As[3][BMT * 32];
    __shared__ bf16 Bs[3][128 * 32];
    const int tid  = threadIdx.x;
    const int lane = tid & 63;
    const int w    = tid >> 6;
    const int wr = w / WC, wc = w % WC;

    const int nwg = gridDim.x * gridDim.y;
    const int bid = blockIdx.x + gridDim.x * blockIdx.y;
    const int logical = (bid & 7) * (nwg >> 3) + (bid >> 3);
    const int m0 = (logical / gridDim.x) * BMT;
    const int n0 = (logical % gridDim.x) * 128;

    f32x4 acc[4][NF] = {};

    const int srow = tid >> 2;
    const int scol = (tid & 3) * 8;
    const bf16* Ap  = A + (size_t)(m0 + srow) * K + scol;
    const bf16* Ap2 = Ap + (size_t)64 * K;      // used only when BMT==128
    const bf16* Bp  = B + (size_t)(n0 + srow) * K + scol;
    const bf16* Bp2 = Bp + (size_t)64 * K;

    const int arow = wr * 64 + (lane & 15);
    const int brow = wc * (NF * 16) + (lane & 15);
    const int kgrp = (lane >> 4) * 16;

    auto stage = [&](int buf, int k0) {
        char* AsB = (char*)As[buf] + w * 1024;
        char* BsB = (char*)Bs[buf] + w * 1024;
        gload16(Ap  + k0, AsB);
        if (BMT == 128) gload16(Ap2 + k0, AsB + 4096);
        gload16(Bp  + k0, BsB);
        gload16(Bp2 + k0, BsB + 4096);
    };

    const int nt = K >> 5;
    stage(0, 0);
    stage(1, 32);
    for (int t = 0; t < nt; ++t) {
        // Wait for own tile-t loads only; tile t+1's (if staged) stay in flight.
        if (t + 1 < nt) {
            if (BMT == 128) asm volatile("s_waitcnt vmcnt(4)" ::: "memory");
            else            asm volatile("s_waitcnt vmcnt(3)" ::: "memory");
        } else {
            asm volatile("s_waitcnt vmcnt(0)" ::: "memory");
        }
        __builtin_amdgcn_s_barrier();       // everyone's tile-t loads landed;
        __builtin_amdgcn_sched_barrier(0);  // everyone finished compute of t-1
        if (t + 2 < nt) stage((t + 2) % 3, (t + 2) << 5);
        const char* Ab = (const char*)As[t % 3];
        const char* Bb = (const char*)Bs[t % 3];
        short8 aF[4], bF[NF];
#pragma unroll
        for (int m = 0; m < 4; ++m)
            aF[m] = *(const short8*)(Ab + ((arow + m * 16) * 64 + kgrp));
#pragma unroll
        for (int n = 0; n < NF; ++n)
            bF[n] = *(const short8*)(Bb + ((brow + n * 16) * 64 + kgrp));
#pragma unroll
        for (int m = 0; m < 4; ++m)
#pragma unroll
            for (int n = 0; n < NF; ++n)
                acc[m][n] = __builtin_amdgcn_mfma_f32_16x16x32_bf16(aF[m], bF[n], acc[m][n], 0, 0, 0);
    }

    const int crow0 = m0 + wr * 64 + (lane >> 4) * 4;
    const int ccol0 = n0 + wc * (NF * 16) + (lane & 15);
#pragma unroll
    for (int m = 0; m < 4; ++m) {
#pragma unroll
        for (int n = 0; n < NF; ++n) {
            const int col = ccol0 + n * 16;
            const int row0 = crow0 + m * 16;
            if (OUT16) {
                int vrow = -1;
                if (VMODE == 1) {
                    const int r = col % 192;
                    if (r >= 128) vrow = (col / 192) * 64 + r - 128;
                } else if (VMODE == 2) {
                    if (col >= 1024) vrow = col - 1024;
                }
                union { ushort4 v; bf16 h[4]; } pk;
#pragma unroll
                for (int j = 0; j < 4; ++j) pk.h[j] = __float2bfloat16(acc[m][n][j]);
                if (VMODE && vrow >= 0) {
                    *(ushort4*)(Vt + (size_t)vrow * ldt + row0) = pk.v;
                } else {
#pragma unroll
                    for (int j = 0; j < 4; ++j)
                        ((bf16*)Cv)[(size_t)(row0 + j) * N + col] = pk.h[j];
                }
            } else {
                const float bv = bias ? bias[col] : 0.f;
#pragma unroll
                for (int j = 0; j < 4; ++j) {
                    const int row = row0 + j;
                    float v = acc[m][n][j] + bv;
                    if (resid) v += resid[(size_t)row * N + col];
                    ((float*)Cv)[(size_t)row * N + col] = v;
                }
            }
        }
    }
}

// --------------- fused flash attention (swapped QK^T, KV tile 64) -----------
// 64 q-rows per block, 4 waves x 16 rows, DH=64, H=16. S^T = mfma(K, Q):
// per lane q = l15, kv = n*16 + l4*4 + reg -> energy is a direct f32x4 NT
// store. Exact defer-max: rescale only when a lane's tile max grew.
template<bool ENERGY>
__global__ __launch_bounds__(256, 4)
void flash_attn(const bf16* __restrict__ Qb, int ldq, int qh_str,
                const bf16* __restrict__ Kb, int ldk, int kh_str, int kh_add,
                const bf16* __restrict__ Vt, int ldvt,
                bf16* __restrict__ O, float* __restrict__ energy,
                int SKV, int SQl, float scale) {
    __shared__ bf16 P[64][136];
    const int tid = threadIdx.x;
    const int lane = tid & 63, wid = tid >> 6;
    const int l15 = lane & 15, l4 = lane >> 4;

    // XCD-aware remap (nwg % 8 == 0)
    const int gx  = gridDim.x;
    const int nwg = gx * gridDim.y;
    const int bid = blockIdx.x + gx * blockIdx.y;
    const int logical = (bid & 7) * (nwg >> 3) + (bid >> 3);
    const int xq = logical % gx;
    const int z  = logical / gx;

    const int b = z >> 4, h = z & 15;
    const int q0 = xq * 64;

    const bf16* Qp = Qb + (size_t)b * SQl * ldq + (size_t)h * qh_str;
    const bf16* Kp = Kb + (size_t)b * SKV * ldk + (size_t)h * kh_str + kh_add;
    const bf16* Vp = Vt + (size_t)h * 64 * ldvt + (size_t)b * SKV;

    short8 aQ[2];
#pragma unroll
    for (int s = 0; s < 2; ++s)
        aQ[s] = *(const short8*)(Qp + (size_t)(q0 + wid * 16 + l15) * ldq + s * 32 + l4 * 8);

    f32x4 oacc[4] = {};
    float mI = -1e30f, lI = 0.f;

    for (int kv0 = 0; kv0 < SKV; kv0 += 64) {
        f32x4 sa[4] = {};
#pragma unroll
        for (int n = 0; n < 4; ++n) {
            const bf16* kr = Kp + (size_t)(kv0 + n * 16 + l15) * ldk + l4 * 8;
            const short8 b0 = *(const short8*)(kr);
            const short8 b1 = *(const short8*)(kr + 32);
            sa[n] = __builtin_amdgcn_mfma_f32_16x16x32_bf16(b0, aQ[0], sa[n], 0, 0, 0);
            sa[n] = __builtin_amdgcn_mfma_f32_16x16x32_bf16(b1, aQ[1], sa[n], 0, 0, 0);
        }
        if (ENERGY) {
            float* er = energy + (size_t)z * SQl * SKV
                      + (size_t)(q0 + wid * 16 + l15) * SKV + kv0 + l4 * 4;
#pragma unroll
            for (int n = 0; n < 4; ++n)
                __builtin_nontemporal_store(sa[n], (f32x4*)(er + n * 16));
        }
        // ---- online softmax, exact defer-max ----
        float mx = fmaxf(fmaxf(fmaxf(sa[0][0], sa[0][1]), fmaxf(sa[0][2], sa[0][3])),
                         fmaxf(fmaxf(sa[1][0], sa[1][1]), fmaxf(sa[1][2], sa[1][3])));
        mx = fmaxf(mx, fmaxf(fmaxf(sa[2][0], sa[2][1]), fmaxf(sa[2][2], sa[2][3])));
        mx = fmaxf(mx, fmaxf(fmaxf(sa[3][0], sa[3][1]), fmaxf(sa[3][2], sa[3][3])));
        mx *= scale;
        mx = fmaxf(mx, __shfl_xor(mx, 16, 64));
        mx = fmaxf(mx, __shfl_xor(mx, 32, 64));
        if (__any(mx > mI)) {          // rescale needed (f != 1 for some row)
            const float nm = fmaxf(mI, mx);
            const float f = __expf(mI - nm);
            mI = nm;
            lI *= f;
#pragma unroll
            for (int j = 0; j < 4; ++j) {
                const float fj = __shfl(f, l4 * 4 + j, 64);
#pragma unroll
                for (int n = 0; n < 4; ++n) oacc[n][j] *= fj;
            }
        }
        float rs = 0.f;
#pragma unroll
        for (int n = 0; n < 4; ++n)
#pragma unroll
            for (int j = 0; j < 4; ++j) {
                const float p = __expf(sa[n][j] * scale - mI);
                sa[n][j] = p;
                rs += p;
            }
        rs += __shfl_xor(rs, 16, 64);
        rs += __shfl_xor(rs, 32, 64);
        lI += rs;
#pragma unroll
        for (int n = 0; n < 4; ++n) {
            union { ushort4 v; bf16 hh[4]; } pk;
            pk.hh[0] = __float2bfloat16(sa[n][0]);
            pk.hh[1] = __float2bfloat16(sa[n][1]);
            pk.hh[2] = __float2bfloat16(sa[n][2]);
            pk.hh[3] = __float2bfloat16(sa[n][3]);
            *(ushort4*)(&P[wid * 16 + l15][n * 16 + l4 * 4]) = pk.v;
        }
#pragma unroll
        for (int ks = 0; ks < 2; ++ks) {
            const short8 aP = *(const short8*)(&P[wid * 16 + l15][ks * 32 + l4 * 8]);
#pragma unroll
            for (int n = 0; n < 4; ++n) {
                const short8 bV = *(const short8*)(Vp + (size_t)(n * 16 + l15) * ldvt + kv0 + ks * 32 + l4 * 8);
                oacc[n] = __builtin_amdgcn_mfma_f32_16x16x32_bf16(aP, bV, oacc[n], 0, 0, 0);
            }
        }
    }
#pragma unroll
    for (int j = 0; j < 4; ++j) {
        const float lj = __shfl(lI, l4 * 4 + j, 64);
        const float rl = 1.f / lj;
        const size_t row = (size_t)b * SQl + q0 + wid * 16 + l4 * 4 + j;
#pragma unroll
        for (int n = 0; n < 4; ++n)
            O[row * 1024 + h * 64 + n * 16 + l15] = __float2bfloat16(oacc[n][j] * rl);
    }
}

extern "C" void kernel_launch(void* const* d_in, const int* in_sizes, int n_in,
                              void* d_out, int out_size, void* d_ws, size_t ws_size,
                              hipStream_t stream) {
    const float* queries  = (const float*)d_in[0];
    const float* contexts = (const float*)d_in[1];
    const float* sa_ln_g  = (const float*)d_in[2];
    const float* sa_ln_b  = (const float*)d_in[3];
    const float* sa_qkv_w = (const float*)d_in[4];
    const float* sa_out_w = (const float*)d_in[5];
    const float* sa_out_b = (const float*)d_in[6];
    const float* ca_ln_g  = (const float*)d_in[7];
    const float* ca_ln_b  = (const float*)d_in[8];
    const float* ca_q_w   = (const float*)d_in[9];
    const float* ca_k_w   = (const float*)d_in[10];
    const float* ca_v_w   = (const float*)d_in[11];
    const float* ca_out_w = (const float*)d_in[12];
    const float* ca_out_b = (const float*)d_in[13];
    const float* ff_ln1_g = (const float*)d_in[14];
    const float* ff_ln1_b = (const float*)d_in[15];
    const float* ff_w1    = (const float*)d_in[16];
    const float* ff_ln2_g = (const float*)d_in[17];
    const float* ff_ln2_b = (const float*)d_in[18];
    const float* ff_w2    = (const float*)d_in[19];

    float* out    = (float*)d_out;                     // 4M floats
    float* energy = out + (size_t)BB * SQ_ * CC;       // 128M floats

    const size_t MEG = 1024 * 1024;

    // ---- ws layout (float units) ----
    float* ws = (float*)d_ws;
    bf16*  X0_16      = (bf16*)ws;                                  // 8M bf16   [0,4M)
    bf16*  o16        = (bf16*)(ws + 4 * MEG);                      // 4M bf16   [4,6M)
    bf16*  ca_out_w16 = (bf16*)(ws + 6 * MEG);                      // 1M        [6,6.5M)
    bf16*  ff_w1_16   = (bf16*)(ws + (13 * MEG) / 2);               // 2M        [6.5,7.5M)
    bf16*  ff_w2_16   = (bf16*)(ws + (15 * MEG) / 2);               // 2M        [7.5,8.5M)
    bf16*  q_ca16     = (bf16*)(ws + (17 * MEG) / 2);               // 4M        [8.5,10.5M)
    bf16*  KV_ca      = (bf16*)(ws + (21 * MEG) / 2);               // 16M       [10.5,18.5M)
    bf16*  Vt_ca      = (bf16*)(ws + (37 * MEG) / 2);               // 8M        [18.5,22.5M)
    float* E_buf      = ws + (45 * MEG) / 2;                        // 4M fp32   [22.5,26.5M)
    float* C_buf      = ws + (53 * MEG) / 2;                        // 8M fp32   [26.5,34.5M)
    bf16*  C_buf16    = (bf16*)C_buf;                               // 8M bf16 (FFN mid)

    // ---- early scratch inside energy region (dead before CA flash) ----
    bf16* EZ         = (bf16*)energy;
    bf16* ctx16      = EZ;                 // 8M
    bf16* qkv16      = EZ + 8  * MEG;      // 12M (v-cols unwritten; Q/K only)
    bf16* Vt_sa      = EZ + 20 * MEG;      // 4M
    bf16* qkv_w16    = EZ + 24 * MEG;      // 3M
    bf16* sa_out_w16 = EZ + 27 * MEG;      // 1M
    bf16* ca_q_w16   = EZ + 28 * MEG;      // 1M
    bf16* ca_k_w16   = EZ + 29 * MEG;      // 1M (ca_k|ca_v adjacent for fused KV GEMM)
    bf16* ca_v_w16   = EZ + 30 * MEG;      // 1M

    const int M1 = BB * SQ_;   // 4096
    const int M2 = BB * SK_;   // 8192
    const dim3 thr(256);

    // ---- all conversions in one dispatch ----
    {
        CvtJobs J;
        const float* srcs[9] = { sa_qkv_w, sa_out_w, ca_q_w, ca_k_w, ca_v_w,
                                 ca_out_w, ff_w1, ff_w2, contexts };
        bf16* dsts[9] = { qkv_w16, sa_out_w16, ca_q_w16, ca_k_w16, ca_v_w16,
                          ca_out_w16, ff_w1_16, ff_w2_16, ctx16 };
        const size_t ns[9] = { 3 * MEG, 1 * MEG, 1 * MEG, 1 * MEG, 1 * MEG,
                               1 * MEG, 2 * MEG, 2 * MEG, 8 * MEG };
        int acc_n8 = 0;
        for (int j = 0; j < 9; ++j) {
            J.src[j] = srcs[j];
            J.dst[j] = dsts[j];
            acc_n8 += (int)(ns[j] / 8);
            J.end[j] = acc_n8;
        }
        J.njobs = 9;
        cvt_all<<<(acc_n8 + 255) / 256, thr, 0, stream>>>(J);
    }

    // ---- Self attention ----
    ln_kernel<1024, float><<<M1, thr, 0, stream>>>(queries, sa_ln_g, sa_ln_b, X0_16, 0);
    // qkv projection; v columns go straight to Vt_sa (transposed)
    gemm_bt16<1, 128, 1><<<dim3(3072 / 128, M1 / 128), thr, 0, stream>>>(
        X0_16, qkv_w16, qkv16, M1, 3072, 1024, nullptr, nullptr, Vt_sa, M1);
    flash_attn<false><<<dim3(SQ_ / 64, BB * HH), thr, 0, stream>>>(
        qkv16, 3072, 192, qkv16, 3072, 192, 64, Vt_sa, M1,
        o16, nullptr, SQ_, SQ_, SCALE);
    gemm_bt16<0, 64, 0><<<dim3(1024 / 128, M1 / 64), thr, 0, stream>>>(
        o16, sa_out_w16, E_buf, M1, CC, CC, sa_out_b, queries, nullptr, 0);

    // ---- Cross attention ----
    ln_kernel<1024, float><<<M1, thr, 0, stream>>>(E_buf, ca_ln_g, ca_ln_b, X0_16, 0);
    gemm_bt16<1, 64, 0><<<dim3(1024 / 128, M1 / 64), thr, 0, stream>>>(
        X0_16, ca_q_w16, q_ca16, M1, CC, CC, nullptr, nullptr, nullptr, 0);
    // fused K|V projection: B = [ca_k_w16; ca_v_w16]; V half transposed to Vt_ca
    gemm_bt16<1, 128, 2><<<dim3(2048 / 128, M2 / 128), thr, 0, stream>>>(
        ctx16, ca_k_w16, KV_ca, M2, 2048, 1024, nullptr, nullptr, Vt_ca, M2);
    flash_attn<true><<<dim3(SQ_ / 64, BB * HH), thr, 0, stream>>>(
        q_ca16, 1024, 64, KV_ca, 2048, 64, 0, Vt_ca, M2,
        o16, energy, SK_, SQ_, SCALE);
    gemm_bt16<0, 64, 0><<<dim3(1024 / 128, M1 / 64), thr, 0, stream>>>(
        o16, ca_out_w16, E_buf, M1, CC, CC, ca_out_b, E_buf, nullptr, 0);

    // ---- FFN ----
    ln_kernel<1024, float><<<M1, thr, 0, stream>>>(E_buf, ff_ln1_g, ff_ln1_b, X0_16, 1);
    gemm_bt16<1, 128, 0><<<dim3(2048 / 128, M1 / 128), thr, 0, stream>>>(
        X0_16, ff_w1_16, C_buf16, M1, 2048, 1024, nullptr, nullptr, nullptr, 0);
    ln_kernel<2048, bf16><<<M1, thr, 0, stream>>>(C_buf16, ff_ln2_g, ff_ln2_b, X0_16, 1);
    gemm_bt16<0, 64, 0><<<dim3(1024 / 128, M1 / 64), thr, 0, stream>>>(
        X0_16, ff_w2_16, out, M1, CC, 2048, nullptr, E_buf, nullptr, 0);
}

// Round 12
// 646.286 us; speedup vs baseline: 1.0225x; 1.0225x over previous
//
#include <hip/hip_runtime.h>
#include <hip/hip_bf16.h>
#include <math.h>

// CrossTransformer block. Round 12: revert GEMM to r10 2-phase loop (r11's
// counted-vmcnt + sched_barrier(0) regressed, per m141/m218 mechanism);
// ff1 -> BMT=64 (4 blocks/CU); T5 setprio around flash MFMA clusters.
// B=4, SQ=1024, SK=2048, C=1024, H=16, DH=64.

namespace {
constexpr int BB  = 4;
constexpr int SQ_ = 1024;
constexpr int SK_ = 2048;
constexpr int CC  = 1024;
constexpr int HH  = 16;
constexpr float SCALE  = 0.03125f;   // 1/sqrt(1024)
constexpr float LN_EPS = 1e-5f;
}

typedef __hip_bfloat16 bf16;
typedef __attribute__((ext_vector_type(8))) short short8;
typedef __attribute__((ext_vector_type(4))) float f32x4;

__device__ __forceinline__ void gload16(const void* g, void* l) {
    __builtin_amdgcn_global_load_lds((const __attribute__((address_space(1))) unsigned int*)g,
                                     (__attribute__((address_space(3))) unsigned int*)l,
                                     16, 0, 0);
}

// ---------------- all fp32 -> bf16 conversions in one kernel ----------------
#define MAXJOBS 10
struct CvtJobs {
    const float* src[MAXJOBS];
    bf16*        dst[MAXJOBS];
    int          end[MAXJOBS];   // cumulative n8 (elements/8)
    int          njobs;
};

__global__ __launch_bounds__(256)
void cvt_all(CvtJobs J) {
    const int i = blockIdx.x * 256 + threadIdx.x;
    if (i >= J.end[J.njobs - 1]) return;
    int j = 0;
    while (i >= J.end[j]) ++j;
    const int base = j ? J.end[j - 1] : 0;
    const int k = i - base;
    const float4 a = ((const float4*)J.src[j])[2 * k];
    const float4 b = ((const float4*)J.src[j])[2 * k + 1];
    union { ushort4 v; bf16 h[4]; } lo, hi;
    lo.h[0] = __float2bfloat16(a.x); lo.h[1] = __float2bfloat16(a.y);
    lo.h[2] = __float2bfloat16(a.z); lo.h[3] = __float2bfloat16(a.w);
    hi.h[0] = __float2bfloat16(b.x); hi.h[1] = __float2bfloat16(b.y);
    hi.h[2] = __float2bfloat16(b.z); hi.h[3] = __float2bfloat16(b.w);
    ((ushort4*)J.dst[j])[2 * k]     = lo.v;
    ((ushort4*)J.dst[j])[2 * k + 1] = hi.v;
}

// ---------------- LayerNorm (+optional SiLU), bf16 out, vector loads --------
__device__ __forceinline__ float4 ld4(const float* p, int idx) {
    return ((const float4*)p)[idx];
}
__device__ __forceinline__ float4 ld4(const bf16* p, int idx) {
    const ushort4 u = ((const ushort4*)p)[idx];
    float4 r;
    r.x = __bfloat162float(*(const bf16*)&u.x);
    r.y = __bfloat162float(*(const bf16*)&u.y);
    r.z = __bfloat162float(*(const bf16*)&u.z);
    r.w = __bfloat162float(*(const bf16*)&u.w);
    return r;
}

template<int NCOLS, typename TI>
__global__ __launch_bounds__(256)
void ln_kernel(const TI* __restrict__ x, const float* __restrict__ g,
               const float* __restrict__ b, bf16* __restrict__ out, int do_silu) {
    constexpr int PER = NCOLS / 1024;   // 4-elem chunks per thread
    const size_t row = blockIdx.x;
    const TI* xr = x + row * NCOLS;
    float4 vals[PER];
    float s = 0.f, ss = 0.f;
#pragma unroll
    for (int i = 0; i < PER; ++i) {
        vals[i] = ld4(xr, threadIdx.x + i * 256);
        s  += vals[i].x + vals[i].y + vals[i].z + vals[i].w;
        ss += vals[i].x * vals[i].x + vals[i].y * vals[i].y
            + vals[i].z * vals[i].z + vals[i].w * vals[i].w;
    }
    for (int off = 32; off > 0; off >>= 1) {
        s  += __shfl_down(s, off, 64);
        ss += __shfl_down(ss, off, 64);
    }
    __shared__ float red[10];
    const int wid = threadIdx.x >> 6, lane = threadIdx.x & 63;
    if (lane == 0) { red[wid] = s; red[wid + 4] = ss; }
    __syncthreads();
    if (threadIdx.x == 0) {
        const float ts  = red[0] + red[1] + red[2] + red[3];
        const float tss = red[4] + red[5] + red[6] + red[7];
        const float mu  = ts / NCOLS;
        const float var = tss / NCOLS - mu * mu;
        red[8] = mu;
        red[9] = rsqrtf(var + LN_EPS);
    }
    __syncthreads();
    const float mu = red[8], rstd = red[9];
    bf16* outr = out + row * NCOLS;
#pragma unroll
    for (int i = 0; i < PER; ++i) {
        const int c = (threadIdx.x + i * 256) * 4;
        const float4 gg = *(const float4*)(g + c);
        const float4 bb = *(const float4*)(b + c);
        float y0 = (vals[i].x - mu) * rstd * gg.x + bb.x;
        float y1 = (vals[i].y - mu) * rstd * gg.y + bb.y;
        float y2 = (vals[i].z - mu) * rstd * gg.z + bb.z;
        float y3 = (vals[i].w - mu) * rstd * gg.w + bb.w;
        if (do_silu) {
            y0 = y0 / (1.f + __expf(-y0));
            y1 = y1 / (1.f + __expf(-y1));
            y2 = y2 / (1.f + __expf(-y2));
            y3 = y3 / (1.f + __expf(-y3));
        }
        union { ushort4 v; bf16 h[4]; } pk;
        pk.h[0] = __float2bfloat16(y0); pk.h[1] = __float2bfloat16(y1);
        pk.h[2] = __float2bfloat16(y2); pk.h[3] = __float2bfloat16(y3);
        *(ushort4*)(outr + c) = pk.v;
    }
}

// ------------- bf16 MFMA GEMM: C[M,N] = A[M,K] @ B[N,K]^T (+bias)(+resid) ---
// 2-phase double-buffered K-loop (r10 structure): stage tile t+1 BEFORE
// computing tile t, single __syncthreads per iteration.
// BMT = 128 (2x2 waves) or 64 (1x4 waves, doubled grid for latency hiding).
// XCD-swizzled blockIdx (grids %8==0).
// VMODE (OUT16 only): v-columns written TRANSPOSED into Vt instead of C.
template<int OUT16, int BMT, int VMODE>
__global__ __launch_bounds__(256)
void gemm_bt16(const bf16* __restrict__ A, const bf16* __restrict__ B,
               void* __restrict__ Cv, int M, int N, int K,
               const float* __restrict__ bias, const float* __restrict__ resid,
               bf16* __restrict__ Vt, int ldt) {
    constexpr int WC = (BMT == 128) ? 2 : 4;   // waves in N dir
    constexpr int NF = (BMT == 128) ? 4 : 2;   // 16-col fragments per wave
    __shared__ bf16 As[2][BMT * 32];
    __shared__ bf16 Bs[2][128 * 32];
    const int tid  = threadIdx.x;
    const int lane = tid & 63;
    const int w    = tid >> 6;
    const int wr = w / WC, wc = w % WC;

    const int nwg = gridDim.x * gridDim.y;
    const int bid = blockIdx.x + gridDim.x * blockIdx.y;
    const int logical = (bid & 7) * (nwg >> 3) + (bid >> 3);
    const int m0 = (logical / gridDim.x) * BMT;
    const int n0 = (logical % gridDim.x) * 128;

    f32x4 acc[4][NF] = {};

    const int srow = tid >> 2;
    const int scol = (tid & 3) * 8;
    const bf16* Ap  = A + (size_t)(m0 + srow) * K + scol;
    const bf16* Ap2 = Ap + (size_t)64 * K;      // used only when BMT==128
    const bf16* Bp  = B + (size_t)(n0 + srow) * K + scol;
    const bf16* Bp2 = Bp + (size_t)64 * K;

    const int arow = wr * 64 + (lane & 15);
    const int brow = wc * (NF * 16) + (lane & 15);
    const int kgrp = (lane >> 4) * 16;

    auto stage = [&](int buf, int k0) {
        char* AsB = (char*)As[buf] + w * 1024;
        char* BsB = (char*)Bs[buf] + w * 1024;
        gload16(Ap  + k0, AsB);
        if (BMT == 128) gload16(Ap2 + k0, AsB + 4096);
        gload16(Bp  + k0, BsB);
        gload16(Bp2 + k0, BsB + 4096);
    };

    const int nt = K >> 5;
    stage(0, 0);
    __syncthreads();
    for (int t = 0; t < nt; ++t) {
        if (t + 1 < nt) stage((t + 1) & 1, (t + 1) << 5);
        const char* Ab = (const char*)As[t & 1];
        const char* Bb = (const char*)Bs[t & 1];
        short8 aF[4], bF[NF];
#pragma unroll
        for (int m = 0; m < 4; ++m)
            aF[m] = *(const short8*)(Ab + ((arow + m * 16) * 64 + kgrp));
#pragma unroll
        for (int n = 0; n < NF; ++n)
            bF[n] = *(const short8*)(Bb + ((brow + n * 16) * 64 + kgrp));
#pragma unroll
        for (int m = 0; m < 4; ++m)
#pragma unroll
            for (int n = 0; n < NF; ++n)
                acc[m][n] = __builtin_amdgcn_mfma_f32_16x16x32_bf16(aF[m], bF[n], acc[m][n], 0, 0, 0);
        __syncthreads();   // drains vmcnt(0): tile t+1 landed; reads of tile t done
    }

    const int crow0 = m0 + wr * 64 + (lane >> 4) * 4;
    const int ccol0 = n0 + wc * (NF * 16) + (lane & 15);
#pragma unroll
    for (int m = 0; m < 4; ++m) {
#pragma unroll
        for (int n = 0; n < NF; ++n) {
            const int col = ccol0 + n * 16;
            const int row0 = crow0 + m * 16;
            if (OUT16) {
                int vrow = -1;
                if (VMODE == 1) {
                    const int r = col % 192;
                    if (r >= 128) vrow = (col / 192) * 64 + r - 128;
                } else if (VMODE == 2) {
                    if (col >= 1024) vrow = col - 1024;
                }
                union { ushort4 v; bf16 h[4]; } pk;
#pragma unroll
                for (int j = 0; j < 4; ++j) pk.h[j] = __float2bfloat16(acc[m][n][j]);
                if (VMODE && vrow >= 0) {
                    *(ushort4*)(Vt + (size_t)vrow * ldt + row0) = pk.v;
                } else {
#pragma unroll
                    for (int j = 0; j < 4; ++j)
                        ((bf16*)Cv)[(size_t)(row0 + j) * N + col] = pk.h[j];
                }
            } else {
                const float bv = bias ? bias[col] : 0.f;
#pragma unroll
                for (int j = 0; j < 4; ++j) {
                    const int row = row0 + j;
                    float v = acc[m][n][j] + bv;
                    if (resid) v += resid[(size_t)row * N + col];
                    ((float*)Cv)[(size_t)row * N + col] = v;
                }
            }
        }
    }
}

// --------------- fused flash attention (swapped QK^T, KV tile 64) -----------
// 64 q-rows per block, 4 waves x 16 rows, DH=64, H=16. S^T = mfma(K, Q):
// per lane q = l15, kv = n*16 + l4*4 + reg -> energy is a direct f32x4 NT
// store. Exact defer-max. T5: setprio(1) around the MFMA clusters (flash
// blocks are never barrier-synced -> scheduler can favor MFMA waves, m191).
template<bool ENERGY>
__global__ __launch_bounds__(256, 4)
void flash_attn(const bf16* __restrict__ Qb, int ldq, int qh_str,
                const bf16* __restrict__ Kb, int ldk, int kh_str, int kh_add,
                const bf16* __restrict__ Vt, int ldvt,
                bf16* __restrict__ O, float* __restrict__ energy,
                int SKV, int SQl, float scale) {
    __shared__ bf16 P[64][136];
    const int tid = threadIdx.x;
    const int lane = tid & 63, wid = tid >> 6;
    const int l15 = lane & 15, l4 = lane >> 4;

    // XCD-aware remap (nwg % 8 == 0)
    const int gx  = gridDim.x;
    const int nwg = gx * gridDim.y;
    const int bid = blockIdx.x + gx * blockIdx.y;
    const int logical = (bid & 7) * (nwg >> 3) + (bid >> 3);
    const int xq = logical % gx;
    const int z  = logical / gx;

    const int b = z >> 4, h = z & 15;
    const int q0 = xq * 64;

    const bf16* Qp = Qb + (size_t)b * SQl * ldq + (size_t)h * qh_str;
    const bf16* Kp = Kb + (size_t)b * SKV * ldk + (size_t)h * kh_str + kh_add;
    const bf16* Vp = Vt + (size_t)h * 64 * ldvt + (size_t)b * SKV;

    short8 aQ[2];
#pragma unroll
    for (int s = 0; s < 2; ++s)
        aQ[s] = *(const short8*)(Qp + (size_t)(q0 + wid * 16 + l15) * ldq + s * 32 + l4 * 8);

    f32x4 oacc[4] = {};
    float mI = -1e30f, lI = 0.f;

    for (int kv0 = 0; kv0 < SKV; kv0 += 64) {
        f32x4 sa[4] = {};
        __builtin_amdgcn_s_setprio(1);
#pragma unroll
        for (int n = 0; n < 4; ++n) {
            const bf16* kr = Kp + (size_t)(kv0 + n * 16 + l15) * ldk + l4 * 8;
            const short8 b0 = *(const short8*)(kr);
            const short8 b1 = *(const short8*)(kr + 32);
            sa[n] = __builtin_amdgcn_mfma_f32_16x16x32_bf16(b0, aQ[0], sa[n], 0, 0, 0);
            sa[n] = __builtin_amdgcn_mfma_f32_16x16x32_bf16(b1, aQ[1], sa[n], 0, 0, 0);
        }
        __builtin_amdgcn_s_setprio(0);
        if (ENERGY) {
            float* er = energy + (size_t)z * SQl * SKV
                      + (size_t)(q0 + wid * 16 + l15) * SKV + kv0 + l4 * 4;
#pragma unroll
            for (int n = 0; n < 4; ++n)
                __builtin_nontemporal_store(sa[n], (f32x4*)(er + n * 16));
        }
        // ---- online softmax, exact defer-max ----
        float mx = fmaxf(fmaxf(fmaxf(sa[0][0], sa[0][1]), fmaxf(sa[0][2], sa[0][3])),
                         fmaxf(fmaxf(sa[1][0], sa[1][1]), fmaxf(sa[1][2], sa[1][3])));
        mx = fmaxf(mx, fmaxf(fmaxf(sa[2][0], sa[2][1]), fmaxf(sa[2][2], sa[2][3])));
        mx = fmaxf(mx, fmaxf(fmaxf(sa[3][0], sa[3][1]), fmaxf(sa[3][2], sa[3][3])));
        mx *= scale;
        mx = fmaxf(mx, __shfl_xor(mx, 16, 64));
        mx = fmaxf(mx, __shfl_xor(mx, 32, 64));
        if (__any(mx > mI)) {          // rescale needed (f != 1 for some row)
            const float nm = fmaxf(mI, mx);
            const float f = __expf(mI - nm);
            mI = nm;
            lI *= f;
#pragma unroll
            for (int j = 0; j < 4; ++j) {
                const float fj = __shfl(f, l4 * 4 + j, 64);
#pragma unroll
                for (int n = 0; n < 4; ++n) oacc[n][j] *= fj;
            }
        }
        float rs = 0.f;
#pragma unroll
        for (int n = 0; n < 4; ++n)
#pragma unroll
            for (int j = 0; j < 4; ++j) {
                const float p = __expf(sa[n][j] * scale - mI);
                sa[n][j] = p;
                rs += p;
            }
        rs += __shfl_xor(rs, 16, 64);
        rs += __shfl_xor(rs, 32, 64);
        lI += rs;
#pragma unroll
        for (int n = 0; n < 4; ++n) {
            union { ushort4 v; bf16 hh[4]; } pk;
            pk.hh[0] = __float2bfloat16(sa[n][0]);
            pk.hh[1] = __float2bfloat16(sa[n][1]);
            pk.hh[2] = __float2bfloat16(sa[n][2]);
            pk.hh[3] = __float2bfloat16(sa[n][3]);
            *(ushort4*)(&P[wid * 16 + l15][n * 16 + l4 * 4]) = pk.v;
        }
        __builtin_amdgcn_s_setprio(1);
#pragma unroll
        for (int ks = 0; ks < 2; ++ks) {
            const short8 aP = *(const short8*)(&P[wid * 16 + l15][ks * 32 + l4 * 8]);
#pragma unroll
            for (int n = 0; n < 4; ++n) {
                const short8 bV = *(const short8*)(Vp + (size_t)(n * 16 + l15) * ldvt + kv0 + ks * 32 + l4 * 8);
                oacc[n] = __builtin_amdgcn_mfma_f32_16x16x32_bf16(aP, bV, oacc[n], 0, 0, 0);
            }
        }
        __builtin_amdgcn_s_setprio(0);
    }
#pragma unroll
    for (int j = 0; j < 4; ++j) {
        const float lj = __shfl(lI, l4 * 4 + j, 64);
        const float rl = 1.f / lj;
        const size_t row = (size_t)b * SQl + q0 + wid * 16 + l4 * 4 + j;
#pragma unroll
        for (int n = 0; n < 4; ++n)
            O[row * 1024 + h * 64 + n * 16 + l15] = __float2bfloat16(oacc[n][j] * rl);
    }
}

extern "C" void kernel_launch(void* const* d_in, const int* in_sizes, int n_in,
                              void* d_out, int out_size, void* d_ws, size_t ws_size,
                              hipStream_t stream) {
    const float* queries  = (const float*)d_in[0];
    const float* contexts = (const float*)d_in[1];
    const float* sa_ln_g  = (const float*)d_in[2];
    const float* sa_ln_b  = (const float*)d_in[3];
    const float* sa_qkv_w = (const float*)d_in[4];
    const float* sa_out_w = (const float*)d_in[5];
    const float* sa_out_b = (const float*)d_in[6];
    const float* ca_ln_g  = (const float*)d_in[7];
    const float* ca_ln_b  = (const float*)d_in[8];
    const float* ca_q_w   = (const float*)d_in[9];
    const float* ca_k_w   = (const float*)d_in[10];
    const float* ca_v_w   = (const float*)d_in[11];
    const float* ca_out_w = (const float*)d_in[12];
    const float* ca_out_b = (const float*)d_in[13];
    const float* ff_ln1_g = (const float*)d_in[14];
    const float* ff_ln1_b = (const float*)d_in[15];
    const float* ff_w1    = (const float*)d_in[16];
    const float* ff_ln2_g = (const float*)d_in[17];
    const float* ff_ln2_b = (const float*)d_in[18];
    const float* ff_w2    = (const float*)d_in[19];

    float* out    = (float*)d_out;                     // 4M floats
    float* energy = out + (size_t)BB * SQ_ * CC;       // 128M floats

    const size_t MEG = 1024 * 1024;

    // ---- ws layout (float units) ----
    float* ws = (float*)d_ws;
    bf16*  X0_16      = (bf16*)ws;                                  // 8M bf16   [0,4M)
    bf16*  o16        = (bf16*)(ws + 4 * MEG);                      // 4M bf16   [4,6M)
    bf16*  ca_out_w16 = (bf16*)(ws + 6 * MEG);                      // 1M        [6,6.5M)
    bf16*  ff_w1_16   = (bf16*)(ws + (13 * MEG) / 2);               // 2M        [6.5,7.5M)
    bf16*  ff_w2_16   = (bf16*)(ws + (15 * MEG) / 2);               // 2M        [7.5,8.5M)
    bf16*  q_ca16     = (bf16*)(ws + (17 * MEG) / 2);               // 4M        [8.5,10.5M)
    bf16*  KV_ca      = (bf16*)(ws + (21 * MEG) / 2);               // 16M       [10.5,18.5M)
    bf16*  Vt_ca      = (bf16*)(ws + (37 * MEG) / 2);               // 8M        [18.5,22.5M)
    float* E_buf      = ws + (45 * MEG) / 2;                        // 4M fp32   [22.5,26.5M)
    float* C_buf      = ws + (53 * MEG) / 2;                        // 8M fp32   [26.5,34.5M)
    bf16*  C_buf16    = (bf16*)C_buf;                               // 8M bf16 (FFN mid)

    // ---- early scratch inside energy region (dead before CA flash) ----
    bf16* EZ         = (bf16*)energy;
    bf16* ctx16      = EZ;                 // 8M
    bf16* qkv16      = EZ + 8  * MEG;      // 12M (v-cols unwritten; Q/K only)
    bf16* Vt_sa      = EZ + 20 * MEG;      // 4M
    bf16* qkv_w16    = EZ + 24 * MEG;      // 3M
    bf16* sa_out_w16 = EZ + 27 * MEG;      // 1M
    bf16* ca_q_w16   = EZ + 28 * MEG;      // 1M
    bf16* ca_k_w16   = EZ + 29 * MEG;      // 1M (ca_k|ca_v adjacent for fused KV GEMM)
    bf16* ca_v_w16   = EZ + 30 * MEG;      // 1M

    const int M1 = BB * SQ_;   // 4096
    const int M2 = BB * SK_;   // 8192
    const dim3 thr(256);

    // ---- all conversions in one dispatch ----
    {
        CvtJobs J;
        const float* srcs[9] = { sa_qkv_w, sa_out_w, ca_q_w, ca_k_w, ca_v_w,
                                 ca_out_w, ff_w1, ff_w2, contexts };
        bf16* dsts[9] = { qkv_w16, sa_out_w16, ca_q_w16, ca_k_w16, ca_v_w16,
                          ca_out_w16, ff_w1_16, ff_w2_16, ctx16 };
        const size_t ns[9] = { 3 * MEG, 1 * MEG, 1 * MEG, 1 * MEG, 1 * MEG,
                               1 * MEG, 2 * MEG, 2 * MEG, 8 * MEG };
        int acc_n8 = 0;
        for (int j = 0; j < 9; ++j) {
            J.src[j] = srcs[j];
            J.dst[j] = dsts[j];
            acc_n8 += (int)(ns[j] / 8);
            J.end[j] = acc_n8;
        }
        J.njobs = 9;
        cvt_all<<<(acc_n8 + 255) / 256, thr, 0, stream>>>(J);
    }

    // ---- Self attention ----
    ln_kernel<1024, float><<<M1, thr, 0, stream>>>(queries, sa_ln_g, sa_ln_b, X0_16, 0);
    // qkv projection; v columns go straight to Vt_sa (transposed)
    gemm_bt16<1, 128, 1><<<dim3(3072 / 128, M1 / 128), thr, 0, stream>>>(
        X0_16, qkv_w16, qkv16, M1, 3072, 1024, nullptr, nullptr, Vt_sa, M1);
    flash_attn<false><<<dim3(SQ_ / 64, BB * HH), thr, 0, stream>>>(
        qkv16, 3072, 192, qkv16, 3072, 192, 64, Vt_sa, M1,
        o16, nullptr, SQ_, SQ_, SCALE);
    gemm_bt16<0, 64, 0><<<dim3(1024 / 128, M1 / 64), thr, 0, stream>>>(
        o16, sa_out_w16, E_buf, M1, CC, CC, sa_out_b, queries, nullptr, 0);

    // ---- Cross attention ----
    ln_kernel<1024, float><<<M1, thr, 0, stream>>>(E_buf, ca_ln_g, ca_ln_b, X0_16, 0);
    gemm_bt16<1, 64, 0><<<dim3(1024 / 128, M1 / 64), thr, 0, stream>>>(
        X0_16, ca_q_w16, q_ca16, M1, CC, CC, nullptr, nullptr, nullptr, 0);
    // fused K|V projection: B = [ca_k_w16; ca_v_w16]; V half transposed to Vt_ca
    gemm_bt16<1, 128, 2><<<dim3(2048 / 128, M2 / 128), thr, 0, stream>>>(
        ctx16, ca_k_w16, KV_ca, M2, 2048, 1024, nullptr, nullptr, Vt_ca, M2);
    flash_attn<true><<<dim3(SQ_ / 64, BB * HH), thr, 0, stream>>>(
        q_ca16, 1024, 64, KV_ca, 2048, 64, 0, Vt_ca, M2,
        o16, energy, SK_, SQ_, SCALE);
    gemm_bt16<0, 64, 0><<<dim3(1024 / 128, M1 / 64), thr, 0, stream>>>(
        o16, ca_out_w16, E_buf, M1, CC, CC, ca_out_b, E_buf, nullptr, 0);

    // ---- FFN ----
    ln_kernel<1024, float><<<M1, thr, 0, stream>>>(E_buf, ff_ln1_g, ff_ln1_b, X0_16, 1);
    gemm_bt16<1, 64, 0><<<dim3(2048 / 128, M1 / 64), thr, 0, stream>>>(
        X0_16, ff_w1_16, C_buf16, M1, 2048, 1024, nullptr, nullptr, nullptr, 0);
    ln_kernel<2048, bf16><<<M1, thr, 0, stream>>>(C_buf16, ff_ln2_g, ff_ln2_b, X0_16, 1);
    gemm_bt16<0, 64, 0><<<dim3(1024 / 128, M1 / 64), thr, 0, stream>>>(
        X0_16, ff_w2_16, out, M1, CC, 2048, nullptr, E_buf, nullptr, 0);
}